// Round 1
// baseline (103.524 us; speedup 1.0000x reference)
//
#include <hip/hip_runtime.h>

// Proximity: mean over B of clipped L2 distance between L2-normalized x row
// and its label's L2-normalized center row.
// dist[i] = sxx/nx^2 + scc/nc^2 - 2*sxc/(nx*nc),  nx=max(sqrt(sxx),eps) etc.

#define EPS_MIN 1e-12f
#define CLAMP_MAX 1e12f

// One wave (64 lanes) per sample; 4 waves per block.
__global__ __launch_bounds__(256) void prox_partial_kernel(
    const float* __restrict__ x,
    const int* __restrict__ labels,
    const float* __restrict__ centers,
    float* __restrict__ partial,
    int Bn, int Dn)
{
    const int wave = threadIdx.x >> 6;      // 0..3
    const int lane = threadIdx.x & 63;
    const int sample = blockIdx.x * 4 + wave;

    __shared__ float wsum[4];

    float dist = 0.0f;
    if (sample < Bn) {
        const float* xr = x + (size_t)sample * Dn;
        const int lbl = labels[sample];
        const float* cr = centers + (size_t)lbl * Dn;

        float sxx = 0.f, scc = 0.f, sxc = 0.f;
        // Dn/4 float4s per row; lane strides by 64 float4s (coalesced 1KB/instr).
        #pragma unroll 4
        for (int f4 = lane; f4 * 4 < Dn; f4 += 64) {
            const int idx = f4 * 4;
            float4 xv = *(const float4*)(xr + idx);
            float4 cv = *(const float4*)(cr + idx);
            sxx += xv.x * xv.x + xv.y * xv.y + xv.z * xv.z + xv.w * xv.w;
            scc += cv.x * cv.x + cv.y * cv.y + cv.z * cv.z + cv.w * cv.w;
            sxc += xv.x * cv.x + xv.y * cv.y + xv.z * cv.z + xv.w * cv.w;
        }
        // 64-lane butterfly reduction
        #pragma unroll
        for (int off = 32; off > 0; off >>= 1) {
            sxx += __shfl_down(sxx, off, 64);
            scc += __shfl_down(scc, off, 64);
            sxc += __shfl_down(sxc, off, 64);
        }
        if (lane == 0) {
            float nx = fmaxf(sqrtf(sxx), EPS_MIN);
            float nc = fmaxf(sqrtf(scc), EPS_MIN);
            float ixx = sxx / (nx * nx);   // (||x||/nx)^2, == 1 unless degenerate
            float icc = scc / (nc * nc);
            float dot = sxc / (nx * nc);
            float d = ixx + icc - 2.0f * dot;
            d = fminf(fmaxf(d, EPS_MIN), CLAMP_MAX);
            dist = d;
        }
    }
    if (lane == 0) wsum[wave] = dist;
    __syncthreads();
    if (threadIdx.x == 0)
        partial[blockIdx.x] = wsum[0] + wsum[1] + wsum[2] + wsum[3];
}

// Single-block deterministic reduction of the partials -> mean.
__global__ __launch_bounds__(256) void prox_final_kernel(
    const float* __restrict__ partial, float* __restrict__ out,
    int n, float inv_B)
{
    float s = 0.f;
    for (int i = threadIdx.x; i < n; i += 256) s += partial[i];

    __shared__ float smem[4];
    #pragma unroll
    for (int off = 32; off > 0; off >>= 1) s += __shfl_down(s, off, 64);
    const int wave = threadIdx.x >> 6;
    const int lane = threadIdx.x & 63;
    if (lane == 0) smem[wave] = s;
    __syncthreads();
    if (threadIdx.x == 0)
        out[0] = (smem[0] + smem[1] + smem[2] + smem[3]) * inv_B;
}

extern "C" void kernel_launch(void* const* d_in, const int* in_sizes, int n_in,
                              void* d_out, int out_size, void* d_ws, size_t ws_size,
                              hipStream_t stream)
{
    const float* x       = (const float*)d_in[0];
    const int*   labels  = (const int*)d_in[1];
    const float* centers = (const float*)d_in[2];
    float* out = (float*)d_out;

    const int Bn = in_sizes[1];            // 16384
    const int Dn = in_sizes[0] / Bn;       // 1024

    const int blocks = (Bn + 3) / 4;       // 4096 blocks, 4 samples each
    float* partial = (float*)d_ws;         // blocks * 4 bytes (<= ws_size)

    prox_partial_kernel<<<blocks, 256, 0, stream>>>(x, labels, centers,
                                                    partial, Bn, Dn);
    prox_final_kernel<<<1, 256, 0, stream>>>(partial, out, blocks,
                                             1.0f / (float)Bn);
}